// Round 12
// baseline (613.513 us; speedup 1.0000x reference)
//
#include <hip/hip_runtime.h>

typedef unsigned int u32;
typedef unsigned short u16;
typedef __attribute__((ext_vector_type(8))) short short8;
typedef __attribute__((ext_vector_type(4))) float f32x4;
typedef __attribute__((ext_vector_type(16))) float f32x16;

#define BB 8
#define KK 32
#define SS 4096
#define HH 2048
#define DD 1024
#define NSC 16       // s-chunks in pooling
#define SC_S 256     // s per chunk
#define CH (BB * KK * HH)  // partial-chunk stride (elements)

// ws layout (bytes)
#define OFF_W16  0ull           // bf16 [b][k][s]          : 2 MiB
#define OFF_WB   (2ull << 20)   // bf16 [d][h] (W^T)       : 4 MiB
#define OFF_PART (6ull << 20)   // bf16 [sc][b][k][h]      : 16 MiB

__device__ __forceinline__ u16 f2bf(float x) {
  u32 u = __float_as_uint(x);
  return (u16)((u + 0x7fffu + ((u >> 16) & 1u)) >> 16);  // RNE
}

__device__ __forceinline__ float bf2f(u16 x) {
  return __uint_as_float(((u32)x) << 16);
}

// ---------------------------------------------------------------------------
// k_prep: dual-role. Blocks [0, 256): ownership -> bf16 weights w16[b][k][s].
// Blocks [256, 768): W[h][d] -> WB[d][h] bf16 via LDS 64x64 transpose.
// ---------------------------------------------------------------------------
__global__ __launch_bounds__(256) void k_prep(const void* __restrict__ own,
                                              u16* __restrict__ w16,
                                              const float* __restrict__ W,
                                              u16* __restrict__ WB) {
  __shared__ float lds[64][65];
  const int t = threadIdx.x;

  if (blockIdx.x < BB * KK) {
    // ---- weights role ----
    const int bk = blockIdx.x;  // b*32 + k
    __shared__ int s_mode;
    __shared__ int s_wcnt[4];
    __shared__ float s_inv;

    if (t < 64) {
      u32 w = ((const u32*)own)[t];
      bool wordok = (w <= 1u) || (w == 0x3f800000u);
      unsigned long long m = __ballot(wordok);
      if (t == 0) s_mode = (m == ~0ull) ? 1 : 0;  // 1: 4-byte elems, 0: bytes
    }
    __syncthreads();
    const int mode = s_mode;

    u32 bits = 0;  // bit j = own[b][k][t*16 + j]
    const size_t base = (size_t)bk * SS + (size_t)t * 16;
    if (mode == 0) {
      uint4 v = *(const uint4*)((const unsigned char*)own + base);
      u32 wa[4] = {v.x, v.y, v.z, v.w};
#pragma unroll
      for (int w = 0; w < 4; ++w)
#pragma unroll
        for (int j = 0; j < 4; ++j)
          if ((wa[w] >> (8 * j)) & 0xffu) bits |= 1u << (4 * w + j);
    } else {
      const u32* p = (const u32*)own + base;
#pragma unroll
      for (int j = 0; j < 16; ++j)
        if (p[j] != 0u) bits |= 1u << j;
    }

    int cnt = __popc(bits);
#pragma unroll
    for (int off = 1; off < 64; off <<= 1) cnt += __shfl_xor(cnt, off);
    if ((t & 63) == 0) s_wcnt[t >> 6] = cnt;
    __syncthreads();
    if (t == 0) {
      int tot = s_wcnt[0] + s_wcnt[1] + s_wcnt[2] + s_wcnt[3];
      s_inv = 1.0f / fmaxf((float)tot, 1.0f);
    }
    __syncthreads();
    const u32 hv = (u32)f2bf(s_inv);

    u32 outw[8];
#pragma unroll
    for (int j = 0; j < 8; ++j) {
      u32 lo = ((bits >> (2 * j)) & 1u) ? hv : 0u;
      u32 hi = ((bits >> (2 * j + 1)) & 1u) ? hv : 0u;
      outw[j] = lo | (hi << 16);
    }
    u32* wo = (u32*)w16 + (size_t)bk * (SS / 2) + (size_t)t * 8;
    uint4 o0 = {outw[0], outw[1], outw[2], outw[3]};
    uint4 o1 = {outw[4], outw[5], outw[6], outw[7]};
    ((uint4*)wo)[0] = o0;
    ((uint4*)wo)[1] = o1;
  } else {
    // ---- W-transpose role ----
    const int bidx = blockIdx.x - BB * KK;   // 0..511
    const int hb = (bidx & 31) * 64, db = (bidx >> 5) * 64;
    const int x = t & 63, y = t >> 6;
#pragma unroll
    for (int j = 0; j < 16; ++j) {
      int r = y + 4 * j;
      lds[r][x] = W[(size_t)(hb + r) * DD + db + x];
    }
    __syncthreads();
#pragma unroll
    for (int j = 0; j < 16; ++j) {
      int r = y + 4 * j;
      WB[(size_t)(db + r) * HH + hb + x] = f2bf(lds[x][r]);
    }
  }
}

// ---------------------------------------------------------------------------
// k_pool: R7's proven core (1024 thr, 16 waves lockstep s-walk, plain loop —
// R11 proved barriers kill it, R9/R6 proved narrow h-spans kill it) with the
// MLP lever: each wave owns TWO 32-h tiles (64 h) -> block row-span 4KB
// contiguous, 16 loads in flight per wave (2x R7), fixing R8's measured
// latency-boundedness (occ 40%, all pipes idle). Grid (2,16,8)=256 blocks,
// 1 block/CU, no barriers. bf16 partial epilogue (R8-verified).
// ---------------------------------------------------------------------------
__global__ __launch_bounds__(1024, 4) void k_pool(const float* __restrict__ plan,
                                                  const u16* __restrict__ w16,
                                                  u16* __restrict__ part) {
  const int hcb = blockIdx.x, sc = blockIdx.y, b = blockIdx.z;
  const int t = threadIdx.x, wv = t >> 6, l = t & 63;
  const int lc = l & 31, half = l >> 5;
  const int h0 = hcb * 1024 + wv * 64;
  const int s0 = sc * SC_S;

  const float* pb = plan + (size_t)b * SS * HH + h0 + lc;
  const u16* wa = w16 + (size_t)(b * KK + lc) * SS;

  f32x16 acc0, acc1;
#pragma unroll
  for (int r = 0; r < 16; ++r) { acc0[r] = 0.0f; acc1[r] = 0.0f; }

  for (int step = 0; step < SC_S / 16; ++step) {
    const int sb = s0 + step * 16 + half * 8;
    // A: lane lc = k-row, 8 contiguous s (shared by both h-tiles)
    short8 a = *(const short8*)(wa + sb);
    // B: lane lc = h-col; two 32-h tiles; 8 s-rows each (stride HH)
    const float* col = pb + (size_t)sb * HH;
    float f0[8], f1[8];
#pragma unroll
    for (int j = 0; j < 8; ++j) {
      f0[j] = col[(size_t)j * HH];
      f1[j] = col[(size_t)j * HH + 32];
    }
    short8 b0, b1;
#pragma unroll
    for (int j = 0; j < 8; ++j) {
      b0[j] = (short)f2bf(f0[j]);
      b1[j] = (short)f2bf(f1[j]);
    }
    acc0 = __builtin_amdgcn_mfma_f32_32x32x16_bf16(a, b0, acc0, 0, 0, 0);
    acc1 = __builtin_amdgcn_mfma_f32_32x32x16_bf16(a, b1, acc1, 0, 0, 0);
  }

  // C layout: col = lane&31, row = (reg&3) + 8*(reg>>2) + 4*(lane>>5)
  u16* po = part + ((size_t)sc * BB + b) * KK * HH + h0 + lc;
#pragma unroll
  for (int r = 0; r < 16; ++r) {
    int krow = (r & 3) + 8 * (r >> 2) + 4 * half;
    po[(size_t)krow * HH] = f2bf(acc0[r]);
    po[(size_t)krow * HH + 32] = f2bf(acc1[r]);
  }
}

// ---------------------------------------------------------------------------
// k_projln: fused partial-reduce + projection + LayerNorm. 16 blocks x 1024
// thr (16 waves). A-fragments built by f32-summing the 16 bf16 partial chunks
// (bit-identical to old reduce+proj path). Wave w computes cols w*64..+63 of
// 16 rows via 4x MFMA 16x16x32 -> LDS [16][1024] (+bias) -> wave w LayerNorms
// row w (l+64q column access: conflict-free).
// ---------------------------------------------------------------------------
__global__ __launch_bounds__(1024) void k_projln(const u16* __restrict__ part,
                                                 const u16* __restrict__ WB,
                                                 const float* __restrict__ bias,
                                                 const float* __restrict__ gamma,
                                                 const float* __restrict__ beta,
                                                 float* __restrict__ out) {
  __shared__ float ldsC[16][1024];
  const int r0 = blockIdx.x * 16;
  const int t = threadIdx.x, w = t >> 6, l = t & 63;
  const int lr = l & 15, lg = l >> 4;
  const int c0 = w * 64;

  const u16* pa = part + (size_t)(r0 + lr) * HH + lg * 8;
  f32x4 acc0 = (f32x4){0.f, 0.f, 0.f, 0.f};
  f32x4 acc1 = acc0, acc2 = acc0, acc3 = acc0;

#pragma unroll 2
  for (int step = 0; step < 64; ++step) {
    // A: sum 16 bf16 partial chunks in f32, RNE-pack to bf16
    float af[8] = {0.f, 0.f, 0.f, 0.f, 0.f, 0.f, 0.f, 0.f};
#pragma unroll
    for (int sc = 0; sc < NSC; ++sc) {
      short8 p = *(const short8*)(pa + (size_t)sc * CH + step * 32);
#pragma unroll
      for (int j = 0; j < 8; ++j) af[j] += bf2f((u16)p[j]);
    }
    short8 a;
#pragma unroll
    for (int j = 0; j < 8; ++j) a[j] = (short)f2bf(af[j]);

    const u16* pw = WB + (size_t)(c0 + lr) * HH + lg * 8 + step * 32;
    short8 b0 = *(const short8*)(pw);
    short8 b1 = *(const short8*)(pw + 16 * HH);
    short8 b2 = *(const short8*)(pw + 32 * HH);
    short8 b3 = *(const short8*)(pw + 48 * HH);
    acc0 = __builtin_amdgcn_mfma_f32_16x16x32_bf16(a, b0, acc0, 0, 0, 0);
    acc1 = __builtin_amdgcn_mfma_f32_16x16x32_bf16(a, b1, acc1, 0, 0, 0);
    acc2 = __builtin_amdgcn_mfma_f32_16x16x32_bf16(a, b2, acc2, 0, 0, 0);
    acc3 = __builtin_amdgcn_mfma_f32_16x16x32_bf16(a, b3, acc3, 0, 0, 0);
  }

  // C layout (16x16x32): col = lane&15 -> output col; row = lg*4 + reg.
#pragma unroll
  for (int j = 0; j < 4; ++j) {
    ldsC[lg * 4 + j][c0 + lr]      = acc0[j] + bias[c0 + lr];
    ldsC[lg * 4 + j][c0 + 16 + lr] = acc1[j] + bias[c0 + 16 + lr];
    ldsC[lg * 4 + j][c0 + 32 + lr] = acc2[j] + bias[c0 + 32 + lr];
    ldsC[lg * 4 + j][c0 + 48 + lr] = acc3[j] + bias[c0 + 48 + lr];
  }
  __syncthreads();

  // LayerNorm: wave w owns row w. Lane l covers cols l + 64*q (q=0..15).
  float x[16];
  float s1 = 0.f, s2 = 0.f;
#pragma unroll
  for (int q = 0; q < 16; ++q) {
    x[q] = ldsC[w][l + 64 * q];
    s1 += x[q];
    s2 += x[q] * x[q];
  }
#pragma unroll
  for (int off = 1; off < 64; off <<= 1) {
    s1 += __shfl_xor(s1, off);
    s2 += __shfl_xor(s2, off);
  }
  const float mu = s1 * (1.0f / DD);
  const float var = s2 * (1.0f / DD) - mu * mu;
  const float rs = rsqrtf(var + 1e-5f);
  float* orow = out + (size_t)(r0 + w) * DD;
#pragma unroll
  for (int q = 0; q < 16; ++q) {
    int c = l + 64 * q;
    orow[c] = (x[q] - mu) * rs * gamma[c] + beta[c];
  }
}

// ---------------------------------------------------------------------------

extern "C" void kernel_launch(void* const* d_in, const int* in_sizes, int n_in,
                              void* d_out, int out_size, void* d_ws, size_t ws_size,
                              hipStream_t stream) {
  (void)in_sizes; (void)n_in; (void)out_size; (void)ws_size;
  const float* plan  = (const float*)d_in[0];
  const void*  own   = d_in[1];
  const float* W     = (const float*)d_in[2];
  const float* bias  = (const float*)d_in[3];
  const float* gamma = (const float*)d_in[4];
  const float* beta  = (const float*)d_in[5];
  float* out = (float*)d_out;
  char* ws = (char*)d_ws;

  u16* w16  = (u16*)(ws + OFF_W16);
  u16* WB   = (u16*)(ws + OFF_WB);
  u16* part = (u16*)(ws + OFF_PART);

  k_prep<<<dim3(BB * KK + (HH / 64) * (DD / 64)), dim3(256), 0, stream>>>(own, w16, W, WB);
  k_pool<<<dim3(2, NSC, BB), dim3(1024), 0, stream>>>(plan, w16, part);
  k_projln<<<dim3(BB * KK / 16), dim3(1024), 0, stream>>>(part, WB, bias, gamma, beta, out);
}

// Round 13
// 203.784 us; speedup vs baseline: 3.0106x; 3.0106x over previous
//
#include <hip/hip_runtime.h>

typedef unsigned int u32;
typedef unsigned short u16;
typedef __attribute__((ext_vector_type(8))) short short8;
typedef __attribute__((ext_vector_type(4))) float f32x4;
typedef __attribute__((ext_vector_type(16))) float f32x16;

#define BB 8
#define KK 32
#define SS 4096
#define HH 2048
#define DD 1024
#define NSC 16       // s-chunks in pooling
#define SC_S 256     // s per chunk
#define CH (BB * KK * HH)  // partial-chunk stride (elements)

// ws layout (bytes)
#define OFF_W16  0ull           // bf16 [b][k][s]          : 2 MiB
#define OFF_WB   (2ull << 20)   // bf16 [d][h] (W^T)       : 4 MiB
#define OFF_PART (6ull << 20)   // bf16 [sc][b][k][h]      : 16 MiB
#define OFF_PQ   (23ull << 20)  // bf16 [row][h] pooled    : 1 MiB

__device__ __forceinline__ u16 f2bf(float x) {
  u32 u = __float_as_uint(x);
  return (u16)((u + 0x7fffu + ((u >> 16) & 1u)) >> 16);  // RNE
}

// ---------------------------------------------------------------------------
// k_prep: dual-role. Blocks [0, 256): ownership -> bf16 weights w16[b][k][s].
// Blocks [256, 768): W[h][d] -> WB[d][h] bf16 via LDS 64x64 transpose.
// ---------------------------------------------------------------------------
__global__ __launch_bounds__(256) void k_prep(const void* __restrict__ own,
                                              u16* __restrict__ w16,
                                              const float* __restrict__ W,
                                              u16* __restrict__ WB) {
  __shared__ float lds[64][65];
  const int t = threadIdx.x;

  if (blockIdx.x < BB * KK) {
    // ---- weights role ----
    const int bk = blockIdx.x;  // b*32 + k
    __shared__ int s_mode;
    __shared__ int s_wcnt[4];
    __shared__ float s_inv;

    if (t < 64) {
      u32 w = ((const u32*)own)[t];
      bool wordok = (w <= 1u) || (w == 0x3f800000u);
      unsigned long long m = __ballot(wordok);
      if (t == 0) s_mode = (m == ~0ull) ? 1 : 0;  // 1: 4-byte elems, 0: bytes
    }
    __syncthreads();
    const int mode = s_mode;

    u32 bits = 0;  // bit j = own[b][k][t*16 + j]
    const size_t base = (size_t)bk * SS + (size_t)t * 16;
    if (mode == 0) {
      uint4 v = *(const uint4*)((const unsigned char*)own + base);
      u32 wa[4] = {v.x, v.y, v.z, v.w};
#pragma unroll
      for (int w = 0; w < 4; ++w)
#pragma unroll
        for (int j = 0; j < 4; ++j)
          if ((wa[w] >> (8 * j)) & 0xffu) bits |= 1u << (4 * w + j);
    } else {
      const u32* p = (const u32*)own + base;
#pragma unroll
      for (int j = 0; j < 16; ++j)
        if (p[j] != 0u) bits |= 1u << j;
    }

    int cnt = __popc(bits);
#pragma unroll
    for (int off = 1; off < 64; off <<= 1) cnt += __shfl_xor(cnt, off);
    if ((t & 63) == 0) s_wcnt[t >> 6] = cnt;
    __syncthreads();
    if (t == 0) {
      int tot = s_wcnt[0] + s_wcnt[1] + s_wcnt[2] + s_wcnt[3];
      s_inv = 1.0f / fmaxf((float)tot, 1.0f);
    }
    __syncthreads();
    const u32 hv = (u32)f2bf(s_inv);

    u32 outw[8];
#pragma unroll
    for (int j = 0; j < 8; ++j) {
      u32 lo = ((bits >> (2 * j)) & 1u) ? hv : 0u;
      u32 hi = ((bits >> (2 * j + 1)) & 1u) ? hv : 0u;
      outw[j] = lo | (hi << 16);
    }
    u32* wo = (u32*)w16 + (size_t)bk * (SS / 2) + (size_t)t * 8;
    uint4 o0 = {outw[0], outw[1], outw[2], outw[3]};
    uint4 o1 = {outw[4], outw[5], outw[6], outw[7]};
    ((uint4*)wo)[0] = o0;
    ((uint4*)wo)[1] = o1;
  } else {
    // ---- W-transpose role ----
    const int bidx = blockIdx.x - BB * KK;   // 0..511
    const int hb = (bidx & 31) * 64, db = (bidx >> 5) * 64;
    const int x = t & 63, y = t >> 6;
#pragma unroll
    for (int j = 0; j < 16; ++j) {
      int r = y + 4 * j;
      lds[r][x] = W[(size_t)(hb + r) * DD + db + x];
    }
    __syncthreads();
#pragma unroll
    for (int j = 0; j < 16; ++j) {
      int r = y + 4 * j;
      WB[(size_t)(db + r) * HH + hb + x] = f2bf(lds[x][r]);
    }
  }
}

// ---------------------------------------------------------------------------
// k_pool: R12's VERIFIED ~42-45us core (inferred from R12 total minus its
// 560us projln): 1024 thr, 16 waves lockstep s-walk, each wave owns TWO 32-h
// tiles (64 h, block row-span 4KB contiguous, 16 loads in flight per wave).
// Grid (2,16,8)=256 blocks, 1 block/CU, no barriers. bf16 partial epilogue.
// DO NOT TOUCH — at its memory floor.
// ---------------------------------------------------------------------------
__global__ __launch_bounds__(1024, 4) void k_pool(const float* __restrict__ plan,
                                                  const u16* __restrict__ w16,
                                                  u16* __restrict__ part) {
  const int hcb = blockIdx.x, sc = blockIdx.y, b = blockIdx.z;
  const int t = threadIdx.x, wv = t >> 6, l = t & 63;
  const int lc = l & 31, half = l >> 5;
  const int h0 = hcb * 1024 + wv * 64;
  const int s0 = sc * SC_S;

  const float* pb = plan + (size_t)b * SS * HH + h0 + lc;
  const u16* wa = w16 + (size_t)(b * KK + lc) * SS;

  f32x16 acc0, acc1;
#pragma unroll
  for (int r = 0; r < 16; ++r) { acc0[r] = 0.0f; acc1[r] = 0.0f; }

  for (int step = 0; step < SC_S / 16; ++step) {
    const int sb = s0 + step * 16 + half * 8;
    // A: lane lc = k-row, 8 contiguous s (shared by both h-tiles)
    short8 a = *(const short8*)(wa + sb);
    // B: lane lc = h-col; two 32-h tiles; 8 s-rows each (stride HH)
    const float* col = pb + (size_t)sb * HH;
    float f0[8], f1[8];
#pragma unroll
    for (int j = 0; j < 8; ++j) {
      f0[j] = col[(size_t)j * HH];
      f1[j] = col[(size_t)j * HH + 32];
    }
    short8 b0, b1;
#pragma unroll
    for (int j = 0; j < 8; ++j) {
      b0[j] = (short)f2bf(f0[j]);
      b1[j] = (short)f2bf(f1[j]);
    }
    acc0 = __builtin_amdgcn_mfma_f32_32x32x16_bf16(a, b0, acc0, 0, 0, 0);
    acc1 = __builtin_amdgcn_mfma_f32_32x32x16_bf16(a, b1, acc1, 0, 0, 0);
  }

  // C layout: col = lane&31, row = (reg&3) + 8*(reg>>2) + 4*(lane>>5)
  u16* po = part + ((size_t)sc * BB + b) * KK * HH + h0 + lc;
#pragma unroll
  for (int r = 0; r < 16; ++r) {
    int krow = (r & 3) + 8 * (r >> 2) + 4 * half;
    po[(size_t)krow * HH] = f2bf(acc0[r]);
    po[(size_t)krow * HH + 32] = f2bf(acc1[r]);
  }
}

// ---------------------------------------------------------------------------
// k_reduce: fold 16 bf16 s-chunk partials, pack pooled rows to bf16.
// 1024 blocks x 256 thr: coalesced u32 reads across threads per chunk
// (R8-proven shape, ~3.5us). R12 proved this CANNOT be fused into a
// 16-block kernel (560us latency disaster).
// ---------------------------------------------------------------------------
__global__ __launch_bounds__(256) void k_reduce(const u16* __restrict__ part,
                                                u32* __restrict__ pq) {
  const int i = blockIdx.x * 256 + threadIdx.x;  // over 256 rows * 1024 h-pairs
  const int row = i >> 10, hp = i & 1023;
  const u16* p = part + (size_t)row * HH + 2 * hp;
  float lo = 0.f, hi = 0.f;
#pragma unroll
  for (int sc = 0; sc < NSC; ++sc) {
    u32 v = *(const u32*)(p + (size_t)sc * CH);
    lo += __uint_as_float((v & 0xffffu) << 16);
    hi += __uint_as_float(v & 0xffff0000u);
  }
  pq[i] = (u32)f2bf(lo) | ((u32)f2bf(hi) << 16);
}

// ---------------------------------------------------------------------------
// k_projln: fused projection + LayerNorm (R11 shape — pq is 1MB, L2-fit).
// 16 blocks x 1024 thr. Wave w: cols w*64..+63 of 16 rows, 4x MFMA 16x16x32
// -> LDS [16][1024] (+bias) -> wave w LayerNorms row w (l+64q: conflict-free).
// ---------------------------------------------------------------------------
__global__ __launch_bounds__(1024) void k_projln(const u16* __restrict__ pq,
                                                 const u16* __restrict__ WB,
                                                 const float* __restrict__ bias,
                                                 const float* __restrict__ gamma,
                                                 const float* __restrict__ beta,
                                                 float* __restrict__ out) {
  __shared__ float ldsC[16][1024];
  const int r0 = blockIdx.x * 16;
  const int t = threadIdx.x, w = t >> 6, l = t & 63;
  const int lr = l & 15, lg = l >> 4;
  const int c0 = w * 64;

  const u16* pa = pq + (size_t)(r0 + lr) * HH + lg * 8;
  f32x4 acc0 = (f32x4){0.f, 0.f, 0.f, 0.f};
  f32x4 acc1 = acc0, acc2 = acc0, acc3 = acc0;

#pragma unroll 2
  for (int step = 0; step < 64; ++step) {
    short8 a = *(const short8*)(pa + step * 32);
    const u16* pw = WB + (size_t)(c0 + lr) * HH + lg * 8 + step * 32;
    short8 b0 = *(const short8*)(pw);
    short8 b1 = *(const short8*)(pw + 16 * HH);
    short8 b2 = *(const short8*)(pw + 32 * HH);
    short8 b3 = *(const short8*)(pw + 48 * HH);
    acc0 = __builtin_amdgcn_mfma_f32_16x16x32_bf16(a, b0, acc0, 0, 0, 0);
    acc1 = __builtin_amdgcn_mfma_f32_16x16x32_bf16(a, b1, acc1, 0, 0, 0);
    acc2 = __builtin_amdgcn_mfma_f32_16x16x32_bf16(a, b2, acc2, 0, 0, 0);
    acc3 = __builtin_amdgcn_mfma_f32_16x16x32_bf16(a, b3, acc3, 0, 0, 0);
  }

  // C layout (16x16x32): col = lane&15 -> output col; row = lg*4 + reg.
#pragma unroll
  for (int j = 0; j < 4; ++j) {
    ldsC[lg * 4 + j][c0 + lr]      = acc0[j] + bias[c0 + lr];
    ldsC[lg * 4 + j][c0 + 16 + lr] = acc1[j] + bias[c0 + 16 + lr];
    ldsC[lg * 4 + j][c0 + 32 + lr] = acc2[j] + bias[c0 + 32 + lr];
    ldsC[lg * 4 + j][c0 + 48 + lr] = acc3[j] + bias[c0 + 48 + lr];
  }
  __syncthreads();

  // LayerNorm: wave w owns row w. Lane l covers cols l + 64*q (q=0..15).
  float x[16];
  float s1 = 0.f, s2 = 0.f;
#pragma unroll
  for (int q = 0; q < 16; ++q) {
    x[q] = ldsC[w][l + 64 * q];
    s1 += x[q];
    s2 += x[q] * x[q];
  }
#pragma unroll
  for (int off = 1; off < 64; off <<= 1) {
    s1 += __shfl_xor(s1, off);
    s2 += __shfl_xor(s2, off);
  }
  const float mu = s1 * (1.0f / DD);
  const float var = s2 * (1.0f / DD) - mu * mu;
  const float rs = rsqrtf(var + 1e-5f);
  float* orow = out + (size_t)(r0 + w) * DD;
#pragma unroll
  for (int q = 0; q < 16; ++q) {
    int c = l + 64 * q;
    orow[c] = (x[q] - mu) * rs * gamma[c] + beta[c];
  }
}

// ---------------------------------------------------------------------------

extern "C" void kernel_launch(void* const* d_in, const int* in_sizes, int n_in,
                              void* d_out, int out_size, void* d_ws, size_t ws_size,
                              hipStream_t stream) {
  (void)in_sizes; (void)n_in; (void)out_size; (void)ws_size;
  const float* plan  = (const float*)d_in[0];
  const void*  own   = d_in[1];
  const float* W     = (const float*)d_in[2];
  const float* bias  = (const float*)d_in[3];
  const float* gamma = (const float*)d_in[4];
  const float* beta  = (const float*)d_in[5];
  float* out = (float*)d_out;
  char* ws = (char*)d_ws;

  u16* w16  = (u16*)(ws + OFF_W16);
  u16* WB   = (u16*)(ws + OFF_WB);
  u16* part = (u16*)(ws + OFF_PART);
  u32* pq   = (u32*)(ws + OFF_PQ);

  k_prep<<<dim3(BB * KK + (HH / 64) * (DD / 64)), dim3(256), 0, stream>>>(own, w16, W, WB);
  k_pool<<<dim3(2, NSC, BB), dim3(1024), 0, stream>>>(plan, w16, part);
  k_reduce<<<dim3((BB * KK * (HH / 2)) / 256), dim3(256), 0, stream>>>(part, pq);
  k_projln<<<dim3(BB * KK / 16), dim3(1024), 0, stream>>>((const u16*)pq, WB, bias, gamma, beta, out);
}

// Round 14
// 84.018 us; speedup vs baseline: 7.3022x; 2.4255x over previous
//
#include <hip/hip_runtime.h>

typedef unsigned int u32;
typedef unsigned short u16;
typedef __attribute__((ext_vector_type(8))) short short8;
typedef __attribute__((ext_vector_type(4))) float f32x4;
typedef __attribute__((ext_vector_type(16))) float f32x16;

#define BB 8
#define KK 32
#define SS 4096
#define HH 2048
#define DD 1024
#define NSC 16       // s-chunks in pooling
#define SC_S 256     // s per chunk
#define CH (BB * KK * HH)  // partial-chunk stride (elements)

// ws layout (bytes)
#define OFF_W16  0ull           // bf16 [b][k][s]          : 2 MiB
#define OFF_WB   (2ull << 20)   // bf16 [d][h] (W^T)       : 4 MiB
#define OFF_PART (6ull << 20)   // bf16 [sc][b][k][h]      : 16 MiB
#define OFF_PQ   (23ull << 20)  // bf16 [row][h] pooled    : 1 MiB
#define OFF_PROJ (24ull << 20)  // f32 [row][d]            : 1 MiB

__device__ __forceinline__ u16 f2bf(float x) {
  u32 u = __float_as_uint(x);
  return (u16)((u + 0x7fffu + ((u >> 16) & 1u)) >> 16);  // RNE
}

// ---------------------------------------------------------------------------
// k_prep: dual-role. Blocks [0, 256): ownership -> bf16 weights w16[b][k][s].
// Blocks [256, 768): W[h][d] -> WB[d][h] bf16 via LDS 64x64 transpose.
// ---------------------------------------------------------------------------
__global__ __launch_bounds__(256) void k_prep(const void* __restrict__ own,
                                              u16* __restrict__ w16,
                                              const float* __restrict__ W,
                                              u16* __restrict__ WB) {
  __shared__ float lds[64][65];
  const int t = threadIdx.x;

  if (blockIdx.x < BB * KK) {
    // ---- weights role ----
    const int bk = blockIdx.x;  // b*32 + k
    __shared__ int s_mode;
    __shared__ int s_wcnt[4];
    __shared__ float s_inv;

    if (t < 64) {
      u32 w = ((const u32*)own)[t];
      bool wordok = (w <= 1u) || (w == 0x3f800000u);
      unsigned long long m = __ballot(wordok);
      if (t == 0) s_mode = (m == ~0ull) ? 1 : 0;  // 1: 4-byte elems, 0: bytes
    }
    __syncthreads();
    const int mode = s_mode;

    u32 bits = 0;  // bit j = own[b][k][t*16 + j]
    const size_t base = (size_t)bk * SS + (size_t)t * 16;
    if (mode == 0) {
      uint4 v = *(const uint4*)((const unsigned char*)own + base);
      u32 wa[4] = {v.x, v.y, v.z, v.w};
#pragma unroll
      for (int w = 0; w < 4; ++w)
#pragma unroll
        for (int j = 0; j < 4; ++j)
          if ((wa[w] >> (8 * j)) & 0xffu) bits |= 1u << (4 * w + j);
    } else {
      const u32* p = (const u32*)own + base;
#pragma unroll
      for (int j = 0; j < 16; ++j)
        if (p[j] != 0u) bits |= 1u << j;
    }

    int cnt = __popc(bits);
#pragma unroll
    for (int off = 1; off < 64; off <<= 1) cnt += __shfl_xor(cnt, off);
    if ((t & 63) == 0) s_wcnt[t >> 6] = cnt;
    __syncthreads();
    if (t == 0) {
      int tot = s_wcnt[0] + s_wcnt[1] + s_wcnt[2] + s_wcnt[3];
      s_inv = 1.0f / fmaxf((float)tot, 1.0f);
    }
    __syncthreads();
    const u32 hv = (u32)f2bf(s_inv);

    u32 outw[8];
#pragma unroll
    for (int j = 0; j < 8; ++j) {
      u32 lo = ((bits >> (2 * j)) & 1u) ? hv : 0u;
      u32 hi = ((bits >> (2 * j + 1)) & 1u) ? hv : 0u;
      outw[j] = lo | (hi << 16);
    }
    u32* wo = (u32*)w16 + (size_t)bk * (SS / 2) + (size_t)t * 8;
    uint4 o0 = {outw[0], outw[1], outw[2], outw[3]};
    uint4 o1 = {outw[4], outw[5], outw[6], outw[7]};
    ((uint4*)wo)[0] = o0;
    ((uint4*)wo)[1] = o1;
  } else {
    // ---- W-transpose role ----
    const int bidx = blockIdx.x - BB * KK;   // 0..511
    const int hb = (bidx & 31) * 64, db = (bidx >> 5) * 64;
    const int x = t & 63, y = t >> 6;
#pragma unroll
    for (int j = 0; j < 16; ++j) {
      int r = y + 4 * j;
      lds[r][x] = W[(size_t)(hb + r) * DD + db + x];
    }
    __syncthreads();
#pragma unroll
    for (int j = 0; j < 16; ++j) {
      int r = y + 4 * j;
      WB[(size_t)(db + r) * HH + hb + x] = f2bf(lds[x][r]);
    }
  }
}

// ---------------------------------------------------------------------------
// k_pool: VERIFIED ~42us core (R12: 613.5 total - 560 measured projln):
// 1024 thr, 16 waves lockstep s-walk, each wave owns TWO 32-h tiles (64 h,
// block row-span 4KB contiguous, 16 loads in flight per wave). Grid
// (2,16,8)=256 blocks, 1 block/CU, no barriers. bf16 partial epilogue.
// DO NOT TOUCH — at its memory floor (284MB @ ~6.3TB/s ~= 45us).
// ---------------------------------------------------------------------------
__global__ __launch_bounds__(1024, 4) void k_pool(const float* __restrict__ plan,
                                                  const u16* __restrict__ w16,
                                                  u16* __restrict__ part) {
  const int hcb = blockIdx.x, sc = blockIdx.y, b = blockIdx.z;
  const int t = threadIdx.x, wv = t >> 6, l = t & 63;
  const int lc = l & 31, half = l >> 5;
  const int h0 = hcb * 1024 + wv * 64;
  const int s0 = sc * SC_S;

  const float* pb = plan + (size_t)b * SS * HH + h0 + lc;
  const u16* wa = w16 + (size_t)(b * KK + lc) * SS;

  f32x16 acc0, acc1;
#pragma unroll
  for (int r = 0; r < 16; ++r) { acc0[r] = 0.0f; acc1[r] = 0.0f; }

  for (int step = 0; step < SC_S / 16; ++step) {
    const int sb = s0 + step * 16 + half * 8;
    // A: lane lc = k-row, 8 contiguous s (shared by both h-tiles)
    short8 a = *(const short8*)(wa + sb);
    // B: lane lc = h-col; two 32-h tiles; 8 s-rows each (stride HH)
    const float* col = pb + (size_t)sb * HH;
    float f0[8], f1[8];
#pragma unroll
    for (int j = 0; j < 8; ++j) {
      f0[j] = col[(size_t)j * HH];
      f1[j] = col[(size_t)j * HH + 32];
    }
    short8 b0, b1;
#pragma unroll
    for (int j = 0; j < 8; ++j) {
      b0[j] = (short)f2bf(f0[j]);
      b1[j] = (short)f2bf(f1[j]);
    }
    acc0 = __builtin_amdgcn_mfma_f32_32x32x16_bf16(a, b0, acc0, 0, 0, 0);
    acc1 = __builtin_amdgcn_mfma_f32_32x32x16_bf16(a, b1, acc1, 0, 0, 0);
  }

  // C layout: col = lane&31, row = (reg&3) + 8*(reg>>2) + 4*(lane>>5)
  u16* po = part + ((size_t)sc * BB + b) * KK * HH + h0 + lc;
#pragma unroll
  for (int r = 0; r < 16; ++r) {
    int krow = (r & 3) + 8 * (r >> 2) + 4 * half;
    po[(size_t)krow * HH] = f2bf(acc0[r]);
    po[(size_t)krow * HH + 32] = f2bf(acc1[r]);
  }
}

// ---------------------------------------------------------------------------
// k_reduce: fold 16 bf16 s-chunk partials, pack pooled rows to bf16.
// 1024 blocks x 256 thr, coalesced. ~4us. R12 proved this cannot live
// inside a 16-block kernel.
// ---------------------------------------------------------------------------
__global__ __launch_bounds__(256) void k_reduce(const u16* __restrict__ part,
                                                u32* __restrict__ pq) {
  const int i = blockIdx.x * 256 + threadIdx.x;  // over 256 rows * 1024 h-pairs
  const int row = i >> 10, hp = i & 1023;
  const u16* p = part + (size_t)row * HH + 2 * hp;
  float lo = 0.f, hi = 0.f;
#pragma unroll
  for (int sc = 0; sc < NSC; ++sc) {
    u32 v = *(const u32*)(p + (size_t)sc * CH);
    lo += __uint_as_float((v & 0xffffu) << 16);
    hi += __uint_as_float(v & 0xffff0000u);
  }
  pq[i] = (u32)f2bf(lo) | ((u32)f2bf(hi) << 16);
}

// ---------------------------------------------------------------------------
// k_proj: R7's proven 256-block MFMA projection (~6us). 256 CUs pull WB from
// L3 in parallel — R11/R13's 16-block fused LN version was ~135us because
// only 16 CUs streamed 33MB (misattribution found in R13 post-mortem).
// ---------------------------------------------------------------------------
__global__ __launch_bounds__(256) void k_proj(const u16* __restrict__ pq,
                                              const u16* __restrict__ WB,
                                              const float* __restrict__ bias,
                                              float* __restrict__ proj) {
  const int rt = blockIdx.x, ctg = blockIdx.y;
  const int t = threadIdx.x, w = t >> 6, l = t & 63;
  const int lr = l & 15, lg = l >> 4;
  const int r0 = rt * 16, c0 = (ctg * 4 + w) * 16;

  const u16* pa = pq + (size_t)(r0 + lr) * HH + lg * 8;
  const u16* pw = WB + (size_t)(c0 + lr) * HH + lg * 8;
  f32x4 acc = (f32x4){0.f, 0.f, 0.f, 0.f};
#pragma unroll 4
  for (int slab = 0; slab < 64; ++slab) {
    short8 a = *(const short8*)(pa + slab * 32);
    short8 bv = *(const short8*)(pw + slab * 32);
    acc = __builtin_amdgcn_mfma_f32_16x16x32_bf16(a, bv, acc, 0, 0, 0);
  }
  const float bs = bias[c0 + lr];
#pragma unroll
  for (int j = 0; j < 4; ++j)
    proj[(size_t)(r0 + lg * 4 + j) * DD + c0 + lr] = acc[j] + bs;
}

// ---------------------------------------------------------------------------
// k_ln: LayerNorm over D=1024, one block per row (exact ref math, f32).
// ---------------------------------------------------------------------------
__global__ __launch_bounds__(256) void k_ln(const float* __restrict__ proj,
                                            const float* __restrict__ gamma,
                                            const float* __restrict__ beta,
                                            float* __restrict__ out) {
  const int row = blockIdx.x, t = threadIdx.x;
  float4 v = ((const float4*)(proj + (size_t)row * DD))[t];
  float s1 = v.x + v.y + v.z + v.w;
  float s2 = v.x * v.x + v.y * v.y + v.z * v.z + v.w * v.w;
#pragma unroll
  for (int off = 1; off < 64; off <<= 1) {
    s1 += __shfl_xor(s1, off);
    s2 += __shfl_xor(s2, off);
  }
  __shared__ float a1[4], a2[4];
  if ((t & 63) == 0) { a1[t >> 6] = s1; a2[t >> 6] = s2; }
  __syncthreads();
  const float S1 = a1[0] + a1[1] + a1[2] + a1[3];
  const float S2 = a2[0] + a2[1] + a2[2] + a2[3];
  const float mu = S1 * (1.0f / DD);
  const float var = S2 * (1.0f / DD) - mu * mu;
  const float rs = rsqrtf(var + 1e-5f);
  float4 g = ((const float4*)gamma)[t];
  float4 be = ((const float4*)beta)[t];
  float4 o;
  o.x = (v.x - mu) * rs * g.x + be.x;
  o.y = (v.y - mu) * rs * g.y + be.y;
  o.z = (v.z - mu) * rs * g.z + be.z;
  o.w = (v.w - mu) * rs * g.w + be.w;
  ((float4*)(out + (size_t)row * DD))[t] = o;
}

// ---------------------------------------------------------------------------

extern "C" void kernel_launch(void* const* d_in, const int* in_sizes, int n_in,
                              void* d_out, int out_size, void* d_ws, size_t ws_size,
                              hipStream_t stream) {
  (void)in_sizes; (void)n_in; (void)out_size; (void)ws_size;
  const float* plan  = (const float*)d_in[0];
  const void*  own   = d_in[1];
  const float* W     = (const float*)d_in[2];
  const float* bias  = (const float*)d_in[3];
  const float* gamma = (const float*)d_in[4];
  const float* beta  = (const float*)d_in[5];
  float* out = (float*)d_out;
  char* ws = (char*)d_ws;

  u16*   w16  = (u16*)(ws + OFF_W16);
  u16*   WB   = (u16*)(ws + OFF_WB);
  u16*   part = (u16*)(ws + OFF_PART);
  u32*   pq   = (u32*)(ws + OFF_PQ);
  float* proj = (float*)(ws + OFF_PROJ);

  k_prep<<<dim3(BB * KK + (HH / 64) * (DD / 64)), dim3(256), 0, stream>>>(own, w16, W, WB);
  k_pool<<<dim3(2, NSC, BB), dim3(1024), 0, stream>>>(plan, w16, part);
  k_reduce<<<dim3((BB * KK * (HH / 2)) / 256), dim3(256), 0, stream>>>(part, pq);
  k_proj<<<dim3(16, 16), dim3(256), 0, stream>>>((const u16*)pq, WB, bias, proj);
  k_ln<<<dim3(BB * KK), dim3(256), 0, stream>>>(proj, gamma, beta, out);
}